// Round 1
// baseline (20.025 us; speedup 1.0000x reference)
//
#include <hip/hip_runtime.h>

#define T_LEN 4096
#define BLOCK 1024
#define EPT 4            // elements per thread = T_LEN / BLOCK
#define NWAVES 16        // BLOCK / 64
#define RADIUS_I 20

__global__ __launch_bounds__(BLOCK)
void aml_row_kernel(const float* __restrict__ vel,
                    const int* __restrict__ bnd,
                    const int* __restrict__ msk,
                    float* __restrict__ partials,  // [2 * gridDim.x]
                    int nrows) {
    const int row  = blockIdx.x;
    const int tid  = threadIdx.x;
    const int lane = tid & 63;
    const int wave = tid >> 6;

    __shared__ unsigned char sb[T_LEN];   // effective boundaries (bnd | ~mask)
    __shared__ float swsum[NWAVES];       // wave scan totals
    __shared__ float sredN[NWAVES];
    __shared__ float sredD[NWAVES];
    __shared__ float sscale;

    const size_t rowoff = (size_t)row * T_LEN;
    const float4 v4 = reinterpret_cast<const float4*>(vel + rowoff)[tid];
    const int4   b4 = reinterpret_cast<const int4*>(bnd + rowoff)[tid];
    const int4   m4 = reinterpret_cast<const int4*>(msk + rowoff)[tid];

    float vv[EPT], mf[EPT];
    unsigned char be[EPT];
    {
        const float vs[EPT] = {v4.x, v4.y, v4.z, v4.w};
        const int   bs[EPT] = {b4.x, b4.y, b4.z, b4.w};
        const int   ms[EPT] = {m4.x, m4.y, m4.z, m4.w};
#pragma unroll
        for (int i = 0; i < EPT; ++i) {
            mf[i] = ms[i] ? 1.0f : 0.0f;
            vv[i] = vs[i] * mf[i];
            be[i] = (bs[i] != 0 || ms[i] == 0) ? 1 : 0;
            sb[tid * EPT + i] = be[i];
        }
    }
    __syncthreads();

    // ---- block-wide inclusive prefix sum of vv (the cumsum) ----
    float p[EPT];
    p[0] = vv[0];
#pragma unroll
    for (int i = 1; i < EPT; ++i) p[i] = p[i - 1] + vv[i];
    const float tsum = p[EPT - 1];

    // wave-level inclusive scan of per-thread sums
    float sc = tsum;
#pragma unroll
    for (int off = 1; off < 64; off <<= 1) {
        float n = __shfl_up(sc, off, 64);
        if (lane >= off) sc += n;
    }
    if (lane == 63) swsum[wave] = sc;
    __syncthreads();

    // wave 0 scans the 16 wave totals (inclusive)
    if (wave == 0 && lane < NWAVES) {
        float w = swsum[lane];
#pragma unroll
        for (int off = 1; off < NWAVES; off <<= 1) {
            float n = __shfl_up(w, off, 64);
            if (lane >= off) w += n;
        }
        swsum[lane] = w;
    }
    __syncthreads();

    const float base = (wave == 0) ? 0.0f : swsum[wave - 1];
    const float lane_excl = sc - tsum;
    float pred[EPT];
#pragma unroll
    for (int i = 0; i < EPT; ++i) pred[i] = base + lane_excl + p[i];

    // ---- distance transform (clamped at 20, so only a +/-20 window matters) ----
    float gt[EPT];
#pragma unroll
    for (int i = 0; i < EPT; ++i) {
        const int t = tid * EPT + i;
        if (be[i]) {
            gt[i] = 0.0f;
        } else {
            int dmin = min(t + 1, T_LEN - t);   // virtual boundaries at -1 and T
            for (int k = 1; k <= RADIUS_I && k < dmin; ++k) {
                bool hit = false;
                if (t - k >= 0 && sb[t - k]) hit = true;
                if (t + k < T_LEN && sb[t + k]) hit = true;
                if (hit) { dmin = k; break; }
            }
            gt[i] = fminf((float)dmin, (float)RADIUS_I);
        }
    }

    // ---- row max of gt -> scale ----
    float dmax = gt[0];
#pragma unroll
    for (int i = 1; i < EPT; ++i) dmax = fmaxf(dmax, gt[i]);
#pragma unroll
    for (int off = 32; off > 0; off >>= 1)
        dmax = fmaxf(dmax, __shfl_xor(dmax, off, 64));
    if (lane == 0) sredN[wave] = dmax;
    __syncthreads();
    if (tid == 0) {
        float m = sredN[0];
        for (int i = 1; i < NWAVES; ++i) m = fmaxf(m, sredN[i]);
        sscale = m + 1e-6f;
    }
    __syncthreads();
    const float scale = sscale;

    // ---- numerator / denominator partial sums ----
    float num = 0.0f, den = 0.0f;
#pragma unroll
    for (int i = 0; i < EPT; ++i) {
        num += fabsf(pred[i] - gt[i]) * mf[i];
        den += mf[i];
    }
#pragma unroll
    for (int off = 32; off > 0; off >>= 1) {
        num += __shfl_xor(num, off, 64);
        den += __shfl_xor(den, off, 64);
    }
    if (lane == 0) { sredN[wave] = num; sredD[wave] = den; }
    __syncthreads();
    if (tid == 0) {
        float ns = 0.0f, ds = 0.0f;
        for (int i = 0; i < NWAVES; ++i) { ns += sredN[i]; ds += sredD[i]; }
        partials[row] = ns / scale;
        partials[nrows + row] = ds;
    }
}

__global__ void aml_finalize(const float* __restrict__ partials, int nrows,
                             float* __restrict__ out) {
    float num = 0.0f, den = 0.0f;
    for (int i = 0; i < nrows; ++i) {
        num += partials[i];
        den += partials[nrows + i];
    }
    out[0] = num / (den + 1e-6f);
}

extern "C" void kernel_launch(void* const* d_in, const int* in_sizes, int n_in,
                              void* d_out, int out_size, void* d_ws, size_t ws_size,
                              hipStream_t stream) {
    const float* vel = (const float*)d_in[0];
    const int*   bnd = (const int*)d_in[1];
    const int*   msk = (const int*)d_in[2];
    const int total = in_sizes[0];
    const int nrows = total / T_LEN;

    float* partials = (float*)d_ws;

    aml_row_kernel<<<nrows, BLOCK, 0, stream>>>(vel, bnd, msk, partials, nrows);
    aml_finalize<<<1, 1, 0, stream>>>(partials, nrows, (float*)d_out);
}